// Round 8
// baseline (11.865 us; speedup 1.0000x reference)
//
#include <hip/hip_runtime.h>

// DGCRNN forward, analytically reduced (complete digraph N=64, deg=63):
//   prop(x) = (x - S)/63 with S = column-sum; only robot node kept =>
//   out[b,o] = sum_f r[f]*Ar[f,o] + S[f]*As[f,o] + cb[o]
//   Ar = W0 + W1/63 + (2/3969 - 1)*W2,  As = -W1/63 + (124/3969)*W2
//
// R7 -> R8 (discriminator): 2 batches per 512-thread block (two 256-thread
// halves, each = R7's pipeline on its own batch; wh2T shared, built coop).
// Grid 512 -> 256 WGs; waves/CU, per-block chain, traffic all unchanged.
// cw loads moved to entry so B0's vmcnt(0) drain covers their cold latency.

#define BDIM 512

typedef __attribute__((ext_vector_type(8))) short bf16x8;
typedef __attribute__((ext_vector_type(4))) float f32x4;
typedef __attribute__((ext_vector_type(4))) unsigned int u32x4;
typedef __attribute__((ext_vector_type(2))) unsigned int u32x2;

static __device__ __forceinline__ unsigned int cvt_pk_bf16(float lo, float hi) {
    unsigned int r;                    // dst.lo16 = bf16(lo) -> memory element 2j
    asm("v_cvt_pk_bf16_f32 %0, %1, %2" : "=v"(r) : "v"(lo), "v"(hi));
    return r;
}

__global__ __launch_bounds__(512, 2) void dgcrnn_mfma(
    const float* __restrict__ robot_x,  // [B,1,9]
    const float* __restrict__ human_x,  // [B,63,5]
    const float* __restrict__ wr1, const float* __restrict__ wr1_b,   // [9,128],[128]
    const float* __restrict__ wr2, const float* __restrict__ wr2_b,   // [128,64],[64]
    const float* __restrict__ wh1, const float* __restrict__ wh1_b,   // [5,128],[128]
    const float* __restrict__ wh2, const float* __restrict__ wh2_b,   // [128,64],[64]
    const float* __restrict__ cw,  const float* __restrict__ cb,      // [3,64,64],[64]
    float* __restrict__ out)                                          // [B,64]
{
    __shared__ float x_lds[2][324];                    // per-half inputs
    __shared__ float wh2b_l[64], wr2b_l[64], cb_l[64];
    __shared__ float rrow[2][128];                     // robot h1 per half
    __shared__ __align__(16) unsigned int wh2T[4096];  // shared: wh2^T bf16x2 swizzled
    __shared__ __align__(16) short fragA[2][8192];     // per-half A-frags; later out_part
    __shared__ __align__(16) float rp_red[2][256];     // per-half robot l2 wave-reduced
    __shared__ float hpart[2][256];                    // per-half human-sum partials

    const int t    = threadIdx.x;
    const int half = t >> 8;          // 0/1: which batch of the pair
    const int tt   = t & 255;         // thread id within half
    const int b2   = blockIdx.x * 2 + half;
    const int l    = tt & 63;
    const int wh_  = (t >> 6) & 3;    // wave index within half (0..3)
    const int o0   = (tt & 15) * 4;   // o-quad base
    const int fgrp = tt >> 4;         // 0..15

    // ---- all global loads hoisted to entry; B0's vmcnt(0) drain covers them ----
    f32x4 wr2q[8];                                     // wr2[fgrp*8+j][o0..+3]
    #pragma unroll
    for (int j = 0; j < 8; ++j)
        wr2q[j] = *(const f32x4*)&wr2[(fgrp * 8 + j) * 64 + o0];

    const int k0 = ((tt >> 6) & 3) * 32 + ((tt >> 4) & 3) * 8;  // this thread's k-oct
    f32x4 wv4[10], bias4[2];                           // wh1 cols k0..k0+7 + bias
    #pragma unroll
    for (int i = 0; i < 5; ++i) {
        wv4[2 * i]     = *(const f32x4*)&wh1[i * 128 + k0];
        wv4[2 * i + 1] = *(const f32x4*)&wh1[i * 128 + k0 + 4];
    }
    bias4[0] = *(const f32x4*)&wh1_b[k0];
    bias4[1] = *(const f32x4*)&wh1_b[k0 + 4];

    float wr1c[9], wr1bb = 0.f;
    if (tt < 128) {                                    // robot layer-1 col tt
        #pragma unroll
        for (int i = 0; i < 9; ++i) wr1c[i] = wr1[i * 128 + tt];
        wr1bb = wr1_b[tt];
    }

    f32x4 cwq[4][3];                                   // cw[k][fgrp*4+ff][o0..+3]
    #pragma unroll
    for (int ff = 0; ff < 4; ++ff)
        #pragma unroll
        for (int k = 0; k < 3; ++k)
            cwq[ff][k] = *(const f32x4*)&cw[k * 4096 + (fgrp * 4 + ff) * 64 + o0];

    // ---- stage: per-half inputs; shared wh2T split across both halves ----
    for (int i = tt; i < 324; i += 256)
        x_lds[half][i] = (i < 9) ? robot_x[b2 * 9 + i] : human_x[b2 * 315 + (i - 9)];
    if (t < 64) { wh2b_l[t] = wh2_b[t]; wr2b_l[t] = wr2_b[t]; cb_l[t] = cb[t]; }
    {
        f32x4 e[2], d[2];
        #pragma unroll
        for (int kk = 0; kk < 2; ++kk) {               // k-pairs kp = fgrp*4+2*half+kk
            int kp = fgrp * 4 + 2 * half + kk;
            e[kk] = *(const f32x4*)&wh2[(2 * kp) * 64 + o0];
            d[kk] = *(const f32x4*)&wh2[(2 * kp + 1) * 64 + o0];
        }
        #pragma unroll
        for (int c = 0; c < 4; ++c) {
            int o = o0 + c;
            u32x2 vv;
            #pragma unroll
            for (int kk = 0; kk < 2; ++kk) vv[kk] = cvt_pk_bf16(e[kk][c], d[kk][c]);
            // (fgrp*4+2h+kk)^mask = ((fgrp*4)^mask)+2h+kk (mask bits >=2) -> b64 store
            *(u32x2*)&wh2T[o * 64 + ((fgrp * 4) ^ ((o & 15) << 2)) + 2 * half] = vv;
        }
    }
    __syncthreads();                                   // B0

    // ---- phase 1: humans layer-1 -> bf16 A-frags (weights in regs) ----
    #pragma unroll
    for (int s = 0; s < 4; ++s) {
        int slot = s * 256 + tt;
        int row  = (s << 4) | (tt & 15);               // human index, 63 = pad
        u32x4 vv = {0u, 0u, 0u, 0u};
        if (row != 63) {
            float a8[8];
            #pragma unroll
            for (int j = 0; j < 8; ++j) a8[j] = bias4[j >> 2][j & 3];
            #pragma unroll
            for (int i = 0; i < 5; ++i) {
                float xv = x_lds[half][9 + row * 5 + i];
                #pragma unroll
                for (int j = 0; j < 8; ++j)
                    a8[j] = fmaf(xv, wv4[2 * i + (j >> 2)][j & 3], a8[j]);
            }
            #pragma unroll
            for (int jw = 0; jw < 4; ++jw)
                vv[jw] = cvt_pk_bf16(fmaxf(a8[2 * jw], 0.f), fmaxf(a8[2 * jw + 1], 0.f));
        }
        *(u32x4*)&fragA[half][slot * 8] = vv;
    }
    if (tt < 128) {                                    // robot h1 from hoisted regs
        float a = wr1bb;
        #pragma unroll
        for (int i = 0; i < 9; ++i) a = fmaf(x_lds[half][i], wr1c[i], a);
        rrow[half][tt] = fmaxf(a, 0.f);
    }
    __syncthreads();                                   // B1

    // ---- phase 2b: humans layer-2 via MFMA (wave-within-half = M-tile) ----
    {
        const int c = l & 15, g = l >> 4, mt = wh_;
        bf16x8 af[4];
        #pragma unroll
        for (int kt = 0; kt < 4; ++kt)
            af[kt] = *reinterpret_cast<const bf16x8*>(
                &fragA[half][((mt * 4 + kt) * 64 + l) * 8]);
        #pragma unroll
        for (int nt = 0; nt < 4; ++nt) {
            const int o = nt * 16 + c;
            f32x4 acc = {0.f, 0.f, 0.f, 0.f};
            #pragma unroll
            for (int kt = 0; kt < 4; ++kt) {
                int kw0 = kt * 16 + g * 4;
                bf16x8 bfv = *reinterpret_cast<const bf16x8*>(
                    &wh2T[o * 64 + (kw0 ^ (c << 2))]);
                acc = __builtin_amdgcn_mfma_f32_16x16x32_bf16(af[kt], bfv, acc, 0, 0, 0);
            }
            float bias = wh2b_l[o];
            float s4 = 0.f;
            #pragma unroll
            for (int reg = 0; reg < 4; ++reg) {
                int node = mt * 16 + g * 4 + reg;      // C/D: row=(lane>>4)*4+reg
                float hv = fmaxf(acc[reg] + bias, 0.f);
                s4 += (node == 63) ? 0.f : hv;
            }
            s4 += __shfl_xor(s4, 16, 64);
            s4 += __shfl_xor(s4, 32, 64);
            if (g == 0) hpart[half][mt * 64 + o] = s4;
        }
    }

    // ---- phase 2a: robot layer-2, wave-level shfl pre-reduction -> 4 rows ----
    {
        f32x4 rp = {0.f, 0.f, 0.f, 0.f};
        #pragma unroll
        for (int j = 0; j < 8; ++j) {
            float hv = rrow[half][fgrp * 8 + j];
            #pragma unroll
            for (int c = 0; c < 4; ++c) rp[c] = fmaf(hv, wr2q[j][c], rp[c]);
        }
        #pragma unroll
        for (int c = 0; c < 4; ++c) {                  // sum 4 fgrps within wave
            float v = rp[c];
            v += __shfl_xor(v, 16, 64);
            v += __shfl_xor(v, 32, 64);
            rp[c] = v;
        }
        if (l < 16) *(f32x4*)&rp_red[half][wh_ * 64 + o0] = rp;
    }
    __syncthreads();                                   // B2

    // ---- phase 3+4 fused: own (r,S) quad + folded-Cheb output matmul ----
    {
        const float c1 = 1.0f / 63.0f;
        const float c2 = 2.0f / 3969.0f - 1.0f;
        const float c3 = 124.0f / 3969.0f;
        f32x4 a4 = {0.f, 0.f, 0.f, 0.f};
        #pragma unroll
        for (int ff = 0; ff < 4; ++ff) {
            int f = fgrp * 4 + ff;
            float rsum = wr2b_l[f] + rp_red[half][f] + rp_red[half][64 + f]
                       + rp_red[half][128 + f] + rp_red[half][192 + f];
            float rv = fmaxf(rsum, 0.f);
            float sv = rv + hpart[half][f] + hpart[half][64 + f]
                     + hpart[half][128 + f] + hpart[half][192 + f];
            #pragma unroll
            for (int c = 0; c < 4; ++c) {
                float w0  = cwq[ff][0][c];
                float w1  = cwq[ff][1][c];
                float w2v = cwq[ff][2][c];
                a4[c] += rv * (w0 + c1 * w1 + c2 * w2v) + sv * (c3 * w2v - c1 * w1);
            }
        }
        #pragma unroll
        for (int c = 0; c < 4; ++c) {                  // sum 4 fgrps within wave
            float v = a4[c];
            v += __shfl_xor(v, 16, 64);
            v += __shfl_xor(v, 32, 64);
            a4[c] = v;
        }
        float* out_part = reinterpret_cast<float*>(fragA[half]);  // dead after 2b
        if (l < 16) *(f32x4*)&out_part[wh_ * 64 + o0] = a4;
    }
    __syncthreads();                                   // B3

    if (tt < 64) {
        const float* out_part = reinterpret_cast<const float*>(fragA[half]);
        out[b2 * 64 + tt] = cb_l[tt] + out_part[tt] + out_part[64 + tt]
                          + out_part[128 + tt] + out_part[192 + tt];
    }
}

extern "C" void kernel_launch(void* const* d_in, const int* in_sizes, int n_in,
                              void* d_out, int out_size, void* d_ws, size_t ws_size,
                              hipStream_t stream) {
    const float* robot_x = (const float*)d_in[0];
    const float* human_x = (const float*)d_in[1];
    // d_in[2] = edge_index (int32) -- fixed complete digraph; unused.
    const float* wr1   = (const float*)d_in[3];
    const float* wr1_b = (const float*)d_in[4];
    const float* wr2   = (const float*)d_in[5];
    const float* wr2_b = (const float*)d_in[6];
    const float* wh1   = (const float*)d_in[7];
    const float* wh1_b = (const float*)d_in[8];
    const float* wh2   = (const float*)d_in[9];
    const float* wh2_b = (const float*)d_in[10];
    const float* cw    = (const float*)d_in[11];
    const float* cb    = (const float*)d_in[12];
    float* out = (float*)d_out;

    dgcrnn_mfma<<<256, BDIM, 0, stream>>>(robot_x, human_x,
                                          wr1, wr1_b, wr2, wr2_b,
                                          wh1, wh1_b, wh2, wh2_b,
                                          cw, cb, out);
}